// Round 13
// baseline (223.590 us; speedup 1.0000x reference)
//
#include <hip/hip_runtime.h>
#include <hip/hip_bf16.h>

#define B_ 4096
#define D_ 32
#define H_ 1024
#define CS 512                 // activation chunk stride: [chunk][16 rows][32] shorts
#define WPK_L 1079296          // shorts per hidden-layer weight pack (= 2048*sum(idx+1))

typedef __attribute__((ext_vector_type(8))) short short8;
typedef __attribute__((ext_vector_type(4))) float floatx4;

// non-draining workgroup barrier: LDS visibility only, leaves global loads in flight
#define BAR() __asm__ __volatile__("s_waitcnt lgkmcnt(0)\n\ts_barrier" ::: "memory")

__device__ inline unsigned short f2bf(float f) {      // fp32 -> bf16 bits, RNE
    unsigned u = __float_as_uint(f);
    unsigned r = (u + 0x7FFF + ((u >> 16) & 1)) >> 16;
    return (unsigned short)r;
}
__device__ inline void glds16(const void* g, void* l) {
    __builtin_amdgcn_global_load_lds(
        (const __attribute__((address_space(1))) unsigned int*)g,
        (__attribute__((address_space(3))) unsigned int*)l, 16, 0, 0);
}

// degree-sorted order: degree 0 -> slots [0,34), degree d>=1 -> slots [33d+1, 33d+34)
__device__ inline int degs(int hp) { return (hp < 34) ? 0 : (hp - 1) / 33; }
__device__ inline int permf(int hp) {                  // sorted slot -> original h
    int d = degs(hp);
    int r = d ? (hp - 33 * d - 1) : hp;
    return d + 31 * r;
}
// chunk-aligned fresh-band base at step idx>=1: covers fresh slots [33(idx-1)+1, 33idx+1)
__device__ inline int band0a(int idx) {
    int nb = (33 * (idx - 1) + 1) & ~31;
    return (nb > H_ - 64) ? H_ - 64 : nb;
}

// ---- prep stage 1 (fused): Wbp, W0 packs, Wopk (finalized-only), Wof32, biases ----
__global__ __launch_bounds__(256) void prep1(
        const float* __restrict__ Wh, const float* __restrict__ W0,
        const float* __restrict__ Wout, const float* __restrict__ b0,
        const float* __restrict__ bh,
        unsigned short* __restrict__ Wbp, unsigned short* __restrict__ W0pk,
        unsigned short* __restrict__ Wopk, float* __restrict__ Wof32,
        float* __restrict__ b0p, float* __restrict__ bhp) {
    __shared__ float row[H_];
    int b = blockIdx.x, t = threadIdx.x;
    if (b < 2048) {                          // Wbp[l][np][kp], staged via LDS (coalesced)
        int l = b >> 10, np = b & 1023;
        const float* src = Wh + ((size_t)l << 20) + ((size_t)permf(np) << 10);
        ((float4*)row)[t] = ((const float4*)src)[t];
        __syncthreads();
        int dn = degs(np);
        unsigned short o[4];
        #pragma unroll
        for (int j = 0; j < 4; j++) {
            int kp = t * 4 + j;
            o[j] = (dn >= degs(kp)) ? f2bf(row[permf(kp)]) : (unsigned short)0;
        }
        ((ushort4*)(Wbp + ((size_t)l << 20) + ((size_t)np << 10)))[t] =
            ushort4{o[0], o[1], o[2], o[3]};
    } else if (b < 2079) {                   // W0 band packs [idx][slot64][32], aligned bands
        int idx = b - 2047;
        int nb0 = band0a(idx);
        int j = t >> 2, ko = (t & 3) * 8;
        int n = nb0 + j;
        int dn = degs(n);
        const float* srow = W0 + (size_t)permf(n) * 32;
        union { unsigned short o[8]; uint4 v; } u;
        #pragma unroll
        for (int e = 0; e < 8; e++)
            u.o[e] = (dn >= ko + e) ? f2bf(srow[ko + e]) : (unsigned short)0;
        *(uint4*)(W0pk + (idx - 1) * 2048 + j * 32 + ko) = u.v;
    } else if (b < 3103) {                   // Wopk [idx][c][col16][32]: finalized region only
        int bb = b - 2079;
        int idx = bb >> 5, c = bb & 31;
        int limit = idx ? band0a(idx) : 0;   // zero for h >= nb0a (fresh handled in-register)
        #pragma unroll
        for (int uu = 0; uu < 2; uu++) {
            int e = t + uu * 256;
            int col = e >> 5, k = e & 31;
            int h = c * 32 + k;
            unsigned short v = 0;
            if (col < 2 && h < limit)
                v = f2bf(Wout[(size_t)(idx + col * 32) * H_ + permf(h)]);
            Wopk[(size_t)bb * 512 + e] = v;
        }
    } else if (b < 3119) {                   // Wof32 [idx][j64][2] fp32 fresh-band out weights
        int e = (b - 3103) * 256 + t;        // 0..4095
        int idx = e >> 7, j = (e >> 1) & 63, c01 = e & 1;
        float v = 0.f;
        if (idx >= 1) {
            int nb = band0a(idx);
            if (nb + j < 33 * idx + 1)
                v = Wout[(size_t)(idx + c01 * 32) * H_ + permf(nb + j)];
        }
        Wof32[e] = v;
    } else {                                 // biases
        int tt = (b - 3119) * 256 + t;       // over 3*1024
        int hp = tt & 1023;
        int p = permf(hp);
        if (tt < 1024) b0p[hp] = b0[p];
        else if (tt < 2048) bhp[hp] = bh[p];
        else bhp[1024 + hp] = bh[1024 + p];
    }
}

// ---- prep stage 2: contiguous repack Wbp -> per-step band packs [c][slot64][32] ----
__global__ __launch_bounds__(256) void prep2(const unsigned short* __restrict__ Wbp,
                                             unsigned short* __restrict__ Wpk) {
    int b = blockIdx.x;                      // 2 layers * 31 idx * 32 chunk slots
    int l = b / 992;
    int r = b - l * 992;
    int idx = (r >> 5) + 1;
    int c = r & 31;
    if (c >= idx + 1) return;                // nk(idx) = idx+1 live chunks
    int nb0 = band0a(idx);
    int t = threadIdx.x;
    int j = t >> 2, ko = (t & 3) * 8;
    uint4 v = *(const uint4*)(Wbp + ((size_t)l << 20) + ((size_t)(nb0 + j) << 10) + c * 32 + ko);
    *(uint4*)(Wpk + (size_t)l * WPK_L + (size_t)1024 * (idx - 1) * (idx + 2)
              + c * 2048 + j * 32 + ko) = v;
}

__device__ inline floatx4 mfma16(short8 a, short8 b, floatx4 c) {
    return __builtin_amdgcn_mfma_f32_16x16x32_bf16(a, b, c, 0, 0, 0);
}

// ---- band K-partial: one wave, 16 slots x 16 rows, chunks [c0,c1) ----
__device__ inline floatx4 band_partial(const unsigned short* act, const unsigned short* wpk,
                                       int frow, int fk, int s, int c0, int c1) {
    const unsigned short* ap = act + frow * 32 + fk * 8;
    const unsigned short* wp = wpk + s * 512 + frow * 32 + fk * 8;
    floatx4 x = {0.f, 0.f, 0.f, 0.f}, y = {0.f, 0.f, 0.f, 0.f};
    int c = c0;
    for (; c + 1 < c1; c += 2) {
        short8 a0 = *(const short8*)(ap + c * CS);
        short8 b0 = *(const short8*)(wp + (size_t)c * 2048);
        short8 a1 = *(const short8*)(ap + (c + 1) * CS);
        short8 b1 = *(const short8*)(wp + (size_t)(c + 1) * 2048);
        x = mfma16(a0, b0, x);
        y = mfma16(a1, b1, y);
    }
    if (c < c1) {
        short8 a0 = *(const short8*)(ap + c * CS);
        short8 b0 = *(const short8*)(wp + (size_t)c * 2048);
        x = mfma16(a0, b0, x);
    }
    return x + y;
}

// ---- mega-kernel: 256 wgs x 16 rows x 16 waves; 5 barriers/step ----
__global__ __launch_bounds__(1024) void mega_kernel(
        const float* __restrict__ z,
        const unsigned short* __restrict__ W0pk,
        const float* __restrict__ b0p,
        const unsigned short* __restrict__ Wpk,
        const float* __restrict__ bhp,
        const unsigned short* __restrict__ Wopk,
        const float* __restrict__ Wof32,
        const float* __restrict__ bout,
        float* __restrict__ xout) {
    __shared__ unsigned short aS[3 * 32 * CS];     // a1,a2,a3: [c][16 rows][32], 32KB each
    __shared__ unsigned short xbS[512];            // running x, bf16
    __shared__ float xsS[512];                     // running x, fp32
    __shared__ float zsS[512];
    __shared__ floatx4 redS[12 * 64];              // K-split partials [q-1][s][lane]
    __shared__ float redO[2 * 512];                // out-dot partials, parity-buffered
    __shared__ float redF[128];                    // fresh-band out-dot [s][col*16+m]
    __shared__ float b0S[1024], bhS[2048], boutS[64];
    __shared__ float wofS[4096];                   // fresh out weights [idx][j64][2]
    __shared__ uint4 dummyS[64];                   // prefetch sink (never read)

    const int tid = threadIdx.x;
    const int wave = tid >> 6, lane = tid & 63;
    const int frow = lane & 15, fk = lane >> 4;
    const int arow = frow * 32 + fk * 8;
    const int s = wave & 3, q = wave >> 2;
    const int m0 = blockIdx.x * 16;

    {   // zero-init state + preload read-only tables to LDS
        uint4 zz = {0u, 0u, 0u, 0u};
        for (int i = tid; i < 3 * 32 * CS / 8; i += 1024) ((uint4*)aS)[i] = zz;
        if (tid < 64)  ((uint4*)xbS)[tid] = zz;
        if (tid < 128) ((uint4*)xsS)[tid] = zz;
        if (tid < 256) ((uint4*)redO)[tid] = zz;
        if (tid < 32)  ((uint4*)redF)[tid] = zz;
        if (tid < 128) ((float4*)zsS)[tid] = ((const float4*)(z + (size_t)m0 * 32))[tid];
        b0S[tid] = b0p[tid];
        bhS[tid] = bhp[tid]; bhS[tid + 1024] = bhp[tid + 1024];
        if (tid < 64) boutS[tid] = bout[tid];
        #pragma unroll
        for (int u = 0; u < 4; u++) wofS[u * 1024 + tid] = Wof32[u * 1024 + tid];
    }
    __syncthreads();

    unsigned short* a1 = aS;
    unsigned short* a2 = aS + 32 * CS;
    unsigned short* a3 = aS + 64 * CS;

    for (int idx = 0; idx < 32; idx++) {
        float* rOp = redO + ((idx & 1) << 9);

        // ---- step-top out-dot over ALL chunks (Wopk zero beyond finalized region) ----
        {
            floatx4 oacc = {0.f, 0.f, 0.f, 0.f};
            #pragma unroll
            for (int cc = 0; cc < 2; cc++) {
                int c = wave * 2 + cc;
                short8 a = *(const short8*)(a3 + c * CS + arow);
                short8 bf = *(const short8*)(Wopk + (size_t)((idx * 32 + c) * 16 + frow) * 32 + fk * 8);
                oacc = mfma16(a, bf, oacc);
            }
            if (frow < 2) {
                #pragma unroll
                for (int r = 0; r < 4; r++)
                    rOp[wave * 32 + frow * 16 + fk * 4 + r] = oacc[r];
            }
        }

        if (idx > 0) {
            const int nb0 = band0a(idx);
            const int slot = nb0 + s * 16 + frow;
            const int nk = idx + 1;
            const int nk4 = (nk + 3) >> 2;
            const int c0 = q * nk4;
            const int c1m = (c0 + nk4 < nk) ? c0 + nk4 : nk;
            const unsigned short* wb2 = Wpk + (size_t)1024 * (idx - 1) * (idx + 2);
            const unsigned short* wb3 = wb2 + WPK_L;
            const int wsl = (slot >> 5) * CS + (slot & 31);

            BAR();                                         // A: a1 (written in prev tail) visible

            // ---- layer 2 band ----
            {
                floatx4 p = band_partial(a1, wb2, frow, fk, s, c0, c1m);
                if (q) redS[((q - 1) * 4 + s) * 64 + lane] = p;
                BAR();                                     // B: partials visible
                if (q == 0) {
                    p = p + redS[s * 64 + lane] + redS[(4 + s) * 64 + lane]
                          + redS[(8 + s) * 64 + lane];
                    float bb = bhS[slot];
                    #pragma unroll
                    for (int r = 0; r < 4; r++)
                        a2[wsl + (fk * 4 + r) * 32] = f2bf(fmaxf(p[r] + bb, 0.f));
                }
                BAR();                                     // C: a2 visible
            }

            // ---- layer 3 band ----
            {
                floatx4 g = band_partial(a2, wb3, frow, fk, s, c0, c1m);
                if (q) redS[((q - 1) * 4 + s) * 64 + lane] = g;

                // L2-warming prefetch of step idx+1 packs (after this step's real loads)
                if (idx < 31) {
                    const int slice = (blockIdx.x >> 3) & 31;
                    const char* w2n = (const char*)(Wpk + (size_t)1024 * idx * (idx + 3));
                    const char* w3n = w2n + (size_t)WPK_L * 2;
                    const int bytesn = (idx + 2) * 4096;
                    const char* won = (const char*)(Wopk + (size_t)(idx + 1) * 32 * 512);
                    int off = (slice & 7) * 16384;
                    if (off < bytesn) {
                        glds16(w2n + off + tid * 16, dummyS);
                        glds16(w3n + off + tid * 16, dummyS);
                    }
                    glds16(won + (slice & 1) * 16384 + tid * 16, dummyS);
                    if (tid < 256) glds16((const char*)(W0pk + idx * 2048) + tid * 16, dummyS);
                }
                BAR();                                     // D: partials visible
                if (q == 0) {
                    g = g + redS[s * 64 + lane] + redS[(4 + s) * 64 + lane]
                          + redS[(8 + s) * 64 + lane];
                    float bb = bhS[1024 + slot];
                    float v[4];
                    #pragma unroll
                    for (int r = 0; r < 4; r++) {
                        v[r] = fmaxf(g[r] + bb, 0.f);
                        a3[wsl + (fk * 4 + r) * 32] = f2bf(v[r]);
                    }
                    // fresh-band out-dot in registers (weights LDS-resident, zero beyond prefix)
                    float wmu = wofS[(idx * 64 + s * 16 + frow) * 2 + 0];
                    float wls = wofS[(idx * 64 + s * 16 + frow) * 2 + 1];
                    float pm[4], pl[4];
                    #pragma unroll
                    for (int r = 0; r < 4; r++) { pm[r] = v[r] * wmu; pl[r] = v[r] * wls; }
                    #pragma unroll
                    for (int off = 1; off < 16; off <<= 1) {
                        #pragma unroll
                        for (int r = 0; r < 4; r++) {
                            pm[r] += __shfl_xor(pm[r], off);
                            pl[r] += __shfl_xor(pl[r], off);
                        }
                    }
                    if (frow == 0) {
                        #pragma unroll
                        for (int r = 0; r < 4; r++) {
                            redF[s * 32 + fk * 4 + r]      = pm[r];
                            redF[s * 32 + 16 + fk * 4 + r] = pl[r];
                        }
                    }
                }
            }
        } else {
            // warm step 1's packs during step 0 (no real band loads pending)
            const int slice = (blockIdx.x >> 3) & 31;
            int off = (slice & 7) * 16384;
            if (off < 2 * 4096) {
                glds16((const char*)Wpk + off + tid * 16, dummyS);
                glds16((const char*)(Wpk + WPK_L) + off + tid * 16, dummyS);
            }
            glds16((const char*)(Wopk + (size_t)32 * 512) + (slice & 1) * 16384 + tid * 16, dummyS);
            if (tid < 256) glds16((const char*)W0pk + tid * 16, dummyS);
        }
        BAR();                                             // F: rOp/redF/a3 visible

        // ---- wave-0 tail: x-update then next step's L1 band (same-wave ordering) ----
        if (tid < 16) {
            float sm = boutS[idx], sl2 = boutS[idx + D_];
            #pragma unroll
            for (int w = 0; w < 16; w++) {
                sm += rOp[w * 32 + tid];
                sl2 += rOp[w * 32 + 16 + tid];
            }
            #pragma unroll
            for (int t4 = 0; t4 < 4; t4++) {
                sm += redF[t4 * 32 + tid];
                sl2 += redF[t4 * 32 + 16 + tid];
            }
            float xi = fmaf(zsS[tid * 32 + idx], expf(sl2), sm);
            xsS[tid * 32 + idx] = xi;
            xbS[tid * 32 + idx] = f2bf(xi);
        }
        if (wave == 0 && idx < 31) {
            const int nb0n = band0a(idx + 1);
            short8 xa = *(const short8*)(xbS + frow * 32 + fk * 8);
            #pragma unroll
            for (int t4 = 0; t4 < 4; t4++) {
                short8 wb = *(const short8*)(W0pk + idx * 2048 + (t4 * 16 + frow) * 32 + fk * 8);
                floatx4 acc = {0.f, 0.f, 0.f, 0.f};
                acc = mfma16(xa, wb, acc);
                int sl = nb0n + t4 * 16 + frow;
                float bb = b0S[sl];
                int ws2 = (sl >> 5) * CS + (sl & 31);
                #pragma unroll
                for (int r = 0; r < 4; r++)
                    a1[ws2 + (fk * 4 + r) * 32] = f2bf(fmaxf(acc[r] + bb, 0.f));
            }
        }
    }

    __syncthreads();
    if (tid < 128)
        ((float4*)(xout + (size_t)m0 * 32))[tid] = ((const float4*)xsS)[tid];
}

extern "C" void kernel_launch(void* const* d_in, const int* in_sizes, int n_in,
                              void* d_out, int out_size, void* d_ws, size_t ws_size,
                              hipStream_t stream) {
    const float* z    = (const float*)d_in[0];
    const float* W0   = (const float*)d_in[1];
    const float* b0   = (const float*)d_in[2];
    const float* Wh   = (const float*)d_in[3];   // [2, H, H]
    const float* bh   = (const float*)d_in[4];   // [2, H]
    const float* Wout = (const float*)d_in[5];   // [64, H]
    const float* bout = (const float*)d_in[6];   // [64]

    float* x = (float*)d_out;                          // [B, D] output
    unsigned short* Wbp  = (unsigned short*)d_ws;      // [2, H, H] permuted+masked bf16
    unsigned short* Wpk  = Wbp + 2 * H_ * H_;          // 2 * WPK_L band packs
    unsigned short* W0pk = Wpk + 2 * WPK_L;            // 31 * 2048
    unsigned short* Wopk = W0pk + 31 * 2048;           // 32 * 32 * 512
    float* Wof32 = (float*)(Wopk + 32 * 32 * 512);     // [32][64][2]
    float* b0p = Wof32 + 4096;                         // [H]
    float* bhp = b0p + H_;                             // [2, H]

    prep1<<<3131, 256, 0, stream>>>(Wh, W0, Wout, b0, bh, Wbp, W0pk, Wopk, Wof32, b0p, bhp);
    prep2<<<2 * 31 * 32, 256, 0, stream>>>(Wbp, Wpk);

    mega_kernel<<<B_ / 16, 1024, 0, stream>>>(z, W0pk, b0p, Wpk, bhp, Wopk, Wof32, bout, x);
}

// Round 14
// 216.865 us; speedup vs baseline: 1.0310x; 1.0310x over previous
//
#include <hip/hip_runtime.h>
#include <hip/hip_bf16.h>

#define B_ 4096
#define D_ 32
#define H_ 1024
#define CS 512                 // activation chunk stride: [chunk][16 rows][32] shorts
#define WPK_L 1079296          // shorts per hidden-layer weight pack (= 2048*sum(idx+1))

typedef __attribute__((ext_vector_type(8))) short short8;
typedef __attribute__((ext_vector_type(4))) float floatx4;

// non-draining workgroup barrier: LDS visibility only, leaves global loads in flight
#define BAR() __asm__ __volatile__("s_waitcnt lgkmcnt(0)\n\ts_barrier" ::: "memory")

__device__ inline unsigned short f2bf(float f) {      // fp32 -> bf16 bits, RNE
    unsigned u = __float_as_uint(f);
    unsigned r = (u + 0x7FFF + ((u >> 16) & 1)) >> 16;
    return (unsigned short)r;
}
__device__ inline void glds16(const void* g, void* l) {
    __builtin_amdgcn_global_load_lds(
        (const __attribute__((address_space(1))) unsigned int*)g,
        (__attribute__((address_space(3))) unsigned int*)l, 16, 0, 0);
}

// degree-sorted order: degree 0 -> slots [0,34), degree d>=1 -> slots [33d+1, 33d+34)
__device__ inline int degs(int hp) { return (hp < 34) ? 0 : (hp - 1) / 33; }
__device__ inline int permf(int hp) {                  // sorted slot -> original h
    int d = degs(hp);
    int r = d ? (hp - 33 * d - 1) : hp;
    return d + 31 * r;
}
__device__ inline int band0i(int idx) {                // fresh-band base slot at step idx>=1
    int nb0 = (idx == 1) ? 0 : 33 * idx - 32;
    return (nb0 > H_ - 64) ? H_ - 64 : nb0;
}

// ---- single fused prep: per-step band packs (direct scatter), W0 packs, Wout packs, biases ----
__global__ __launch_bounds__(256) void prep_all(
        const float* __restrict__ Wh, const float* __restrict__ W0,
        const float* __restrict__ Wout, const float* __restrict__ b0,
        const float* __restrict__ bh,
        unsigned short* __restrict__ Wpk, unsigned short* __restrict__ W0pk,
        unsigned short* __restrict__ Wopk, float* __restrict__ b0p,
        float* __restrict__ bhp) {
    __shared__ float row[H_];
    __shared__ unsigned short rb[H_];
    int b = blockIdx.x, t = threadIdx.x;
    if (b < 2048) {                          // Wh row (l, np) -> direct scatter into band packs
        int l = b >> 10, np = b & 1023;
        const float* src = Wh + ((size_t)l << 20) + ((size_t)permf(np) << 10);
        ((float4*)row)[t] = ((const float4*)src)[t];
        __syncthreads();
        int dn = degs(np);
        unsigned short o[4];
        #pragma unroll
        for (int j = 0; j < 4; j++) {
            int kp = t * 4 + j;
            o[j] = (dn >= degs(kp)) ? f2bf(row[permf(kp)]) : (unsigned short)0;
        }
        ((ushort4*)rb)[t] = ushort4{o[0], o[1], o[2], o[3]};
        __syncthreads();
        // row np lives in band windows [nb0, nb0+64) for ~2 idx values; write its segments
        for (int idx = 1; idx < 32; idx++) {
            int nb0 = band0i(idx);
            int j = np - nb0;
            if (j < 0 || j >= 64) continue;              // uniform per block
            int nq = (idx + 1) * 4;                      // 16B quads: nk chunks x 64B
            if (t < nq) {
                int c = t >> 2, qd = t & 3;
                size_t base = (size_t)l * WPK_L + (size_t)1024 * (idx - 1) * (idx + 2);
                *(uint4*)(Wpk + base + c * 2048 + j * 32 + qd * 8) =
                    *(const uint4*)(rb + c * 32 + qd * 8);
            }
        }
    } else if (b < 2079) {                   // W0 band packs [idx][slot64][32]
        int idx = b - 2047;
        int nb0 = band0i(idx);
        int j = t >> 2, ko = (t & 3) * 8;
        int n = nb0 + j;
        int dn = degs(n);
        const float* srow = W0 + (size_t)permf(n) * 32;
        union { unsigned short o[8]; uint4 v; } u;
        #pragma unroll
        for (int e = 0; e < 8; e++)
            u.o[e] = (dn >= ko + e) ? f2bf(srow[ko + e]) : (unsigned short)0;
        *(uint4*)(W0pk + (idx - 1) * 2048 + j * 32 + ko) = u.v;
    } else if (b < 3103) {                   // Wout bf16 packs [idx][c][col16][32], full prefix
        int bb = b - 2079;
        int idx = bb >> 5, c = bb & 31;
        int ns = idx ? 33 * idx + 1 : 0;     // live-prefix length at step idx
        #pragma unroll
        for (int uu = 0; uu < 2; uu++) {
            int e = t + uu * 256;
            int col = e >> 5, k = e & 31;
            int h = c * 32 + k;
            unsigned short v = 0;
            if (col < 2 && h < ns)
                v = f2bf(Wout[(size_t)(idx + col * 32) * H_ + permf(h)]);
            Wopk[(size_t)bb * 512 + e] = v;
        }
    } else {                                 // biases
        int tt = (b - 3103) * 256 + t;       // over 3*1024
        int hp = tt & 1023;
        int p = permf(hp);
        if (tt < 1024) b0p[hp] = b0[p];
        else if (tt < 2048) bhp[hp] = bh[p];
        else bhp[1024 + hp] = bh[1024 + p];
    }
}

__device__ inline floatx4 mfma16(short8 a, short8 b, floatx4 c) {
    return __builtin_amdgcn_mfma_f32_16x16x32_bf16(a, b, c, 0, 0, 0);
}

// ---- band K-partial: one wave, 16 slots x 16 rows, chunks [c0,c1) ----
__device__ inline floatx4 band_partial(const unsigned short* act, const unsigned short* wpk,
                                       int frow, int fk, int s, int c0, int c1) {
    const unsigned short* ap = act + frow * 32 + fk * 8;
    const unsigned short* wp = wpk + s * 512 + frow * 32 + fk * 8;
    floatx4 x = {0.f, 0.f, 0.f, 0.f}, y = {0.f, 0.f, 0.f, 0.f};
    int c = c0;
    for (; c + 1 < c1; c += 2) {
        short8 a0 = *(const short8*)(ap + c * CS);
        short8 b0 = *(const short8*)(wp + (size_t)c * 2048);
        short8 a1 = *(const short8*)(ap + (c + 1) * CS);
        short8 b1 = *(const short8*)(wp + (size_t)(c + 1) * 2048);
        x = mfma16(a0, b0, x);
        y = mfma16(a1, b1, y);
    }
    if (c < c1) {
        short8 a0 = *(const short8*)(ap + c * CS);
        short8 b0 = *(const short8*)(wp + (size_t)c * 2048);
        x = mfma16(a0, b0, x);
    }
    return x + y;
}

// ---- mega-kernel: 256 wgs x 16 rows x 16 waves; 32-step chain in LDS (R12 structure) ----
__global__ __launch_bounds__(1024) void mega_kernel(
        const float* __restrict__ z,
        const unsigned short* __restrict__ W0pk,
        const float* __restrict__ b0p,
        const unsigned short* __restrict__ Wpk,
        const float* __restrict__ bhp,
        const unsigned short* __restrict__ Wopk,
        const float* __restrict__ bout,
        float* __restrict__ xout) {
    __shared__ unsigned short aS[3 * 32 * CS];     // a1,a2,a3: [c][16 rows][32], 32KB each
    __shared__ unsigned short xbS[16 * 32];        // running x, bf16
    __shared__ float xsS[512];                     // running x, fp32
    __shared__ float zsS[512];
    __shared__ floatx4 redS[12 * 64];              // K-split partials [q-1][s][lane]
    __shared__ float redO[16 * 32];                // out-dot partials [wave][col*16+m]
    __shared__ uint4 dummyS[64];                   // prefetch sink (never read)

    const int tid = threadIdx.x;
    const int wave = tid >> 6, lane = tid & 63;
    const int frow = lane & 15, fk = lane >> 4;
    const int arow = frow * 32 + fk * 8;
    const int s = wave & 3, q = wave >> 2;
    const int m0 = blockIdx.x * 16;

    {   // zero-init (garbage x 0-weight must stay 0; matches x0 = 0)
        uint4 zz = {0u, 0u, 0u, 0u};
        for (int i = tid; i < 3 * 32 * CS / 8; i += 1024) ((uint4*)aS)[i] = zz;
        if (tid < 64)  ((uint4*)xbS)[tid] = zz;
        if (tid < 128) ((uint4*)xsS)[tid] = zz;
        if (tid < 128) ((uint4*)redO)[tid] = zz;
        if (tid < 128) ((float4*)zsS)[tid] = ((const float4*)(z + (size_t)m0 * 32))[tid];
    }
    __syncthreads();

    unsigned short* a1 = aS;
    unsigned short* a2 = aS + 32 * CS;
    unsigned short* a3 = aS + 64 * CS;

    for (int idx = 0; idx < 32; idx++) {
        if (idx > 0) {
            const int nb0 = band0i(idx);
            const int slot = nb0 + s * 16 + frow;
            const int nk = idx + 1;
            const int nk4 = (nk + 3) >> 2;
            const int c0 = q * nk4;
            const int c1m = (c0 + nk4 < nk) ? c0 + nk4 : nk;
            const unsigned short* wb2 = Wpk + (size_t)1024 * (idx - 1) * (idx + 2);
            const unsigned short* wb3 = wb2 + WPK_L;
            const int wsl = (slot >> 5) * CS + (slot & 31);

            // ---- layer 1 band (q==0): K=32 single chunk ----
            if (q == 0) {
                short8 a = *(const short8*)(xbS + frow * 32 + fk * 8);
                short8 bf = *(const short8*)(W0pk + (idx - 1) * 2048 + (s * 16 + frow) * 32 + fk * 8);
                floatx4 acc = {0.f, 0.f, 0.f, 0.f};
                acc = mfma16(a, bf, acc);
                float bb = b0p[slot];
                #pragma unroll
                for (int r = 0; r < 4; r++)
                    a1[wsl + (fk * 4 + r) * 32] = f2bf(fmaxf(acc[r] + bb, 0.f));
            }
            BAR();                                         // A: a1 visible

            // ---- layer 2 band ----
            {
                floatx4 p = band_partial(a1, wb2, frow, fk, s, c0, c1m);
                if (q) redS[((q - 1) * 4 + s) * 64 + lane] = p;
                BAR();                                     // B: partials visible
                if (q == 0) {
                    p = p + redS[s * 64 + lane] + redS[(4 + s) * 64 + lane]
                          + redS[(8 + s) * 64 + lane];
                    float bb = bhp[slot];
                    #pragma unroll
                    for (int r = 0; r < 4; r++)
                        a2[wsl + (fk * 4 + r) * 32] = f2bf(fmaxf(p[r] + bb, 0.f));
                }
                BAR();                                     // C: a2 visible
            }

            // ---- layer 3 band ----
            {
                floatx4 g = band_partial(a2, wb3, frow, fk, s, c0, c1m);
                if (q) redS[((q - 1) * 4 + s) * 64 + lane] = g;
                BAR();                                     // D: partials visible
                if (q == 0) {
                    g = g + redS[s * 64 + lane] + redS[(4 + s) * 64 + lane]
                          + redS[(8 + s) * 64 + lane];
                    float bb = bhp[H_ + slot];
                    #pragma unroll
                    for (int r = 0; r < 4; r++)
                        a3[wsl + (fk * 4 + r) * 32] = f2bf(fmaxf(g[r] + bb, 0.f));
                }
                BAR();                                     // E: a3 visible
            }
        }

        // ---- out-dot: wave w covers a3 chunks {2w, 2w+1}; dead-chunk weights are zero ----
        {
            floatx4 oacc = {0.f, 0.f, 0.f, 0.f};
            #pragma unroll
            for (int cc = 0; cc < 2; cc++) {
                int c = wave * 2 + cc;
                short8 a = *(const short8*)(a3 + c * CS + arow);
                short8 bf = *(const short8*)(Wopk + (size_t)((idx * 32 + c) * 16 + frow) * 32 + fk * 8);
                oacc = mfma16(a, bf, oacc);
            }
            if (frow < 2) {
                #pragma unroll
                for (int r = 0; r < 4; r++)
                    redO[wave * 32 + frow * 16 + fk * 4 + r] = oacc[r];
            }
        }

        // ---- L2-warming prefetch of step idx+1 packs (fire-and-forget; issued last) ----
        if (idx < 31) {
            const int slice = (blockIdx.x >> 3) & 31;      // 32 WGs/XCD tile the pack
            const char* w2n = (const char*)(Wpk + (size_t)1024 * idx * (idx + 3));
            const char* w3n = w2n + (size_t)WPK_L * 2;
            const int bytesn = (idx + 2) * 4096;
            const char* won = (const char*)(Wopk + (size_t)(idx + 1) * 32 * 512);
            int off = (slice & 7) * 16384;
            if (off < bytesn) {
                glds16(w2n + off + tid * 16, dummyS);
                glds16(w3n + off + tid * 16, dummyS);
            }
            glds16(won + (slice & 1) * 16384 + tid * 16, dummyS);
        }
        BAR();                                             // F: redO visible

        if (tid < 16) {
            float sm = bout[idx], sl = bout[idx + D_];
            #pragma unroll
            for (int w = 0; w < 16; w++) {
                sm += redO[w * 32 + tid];
                sl += redO[w * 32 + 16 + tid];
            }
            float xi = fmaf(zsS[tid * 32 + idx], expf(sl), sm);
            xsS[tid * 32 + idx] = xi;
            xbS[tid * 32 + idx] = f2bf(xi);
        }
        BAR();                                             // G: x visible
    }

    __syncthreads();
    if (tid < 128)
        ((float4*)(xout + (size_t)m0 * 32))[tid] = ((const float4*)xsS)[tid];
}

extern "C" void kernel_launch(void* const* d_in, const int* in_sizes, int n_in,
                              void* d_out, int out_size, void* d_ws, size_t ws_size,
                              hipStream_t stream) {
    const float* z    = (const float*)d_in[0];
    const float* W0   = (const float*)d_in[1];
    const float* b0   = (const float*)d_in[2];
    const float* Wh   = (const float*)d_in[3];   // [2, H, H]
    const float* bh   = (const float*)d_in[4];   // [2, H]
    const float* Wout = (const float*)d_in[5];   // [64, H]
    const float* bout = (const float*)d_in[6];   // [64]

    float* x = (float*)d_out;                          // [B, D] output
    unsigned short* Wpk  = (unsigned short*)d_ws;      // 2 * WPK_L band packs
    unsigned short* W0pk = Wpk + 2 * WPK_L;            // 31 * 2048
    unsigned short* Wopk = W0pk + 31 * 2048;           // 32 * 32 * 512
    float* b0p = (float*)(Wopk + 32 * 32 * 512);       // [H]
    float* bhp = b0p + H_;                             // [2, H]

    prep_all<<<3115, 256, 0, stream>>>(Wh, W0, Wout, b0, bh, Wpk, W0pk, Wopk, b0p, bhp);

    mega_kernel<<<B_ / 16, 1024, 0, stream>>>(z, W0pk, b0p, Wpk, bhp, Wopk, bout, x);
}